// Round 1
// baseline (338.832 us; speedup 1.0000x reference)
//
#include <hip/hip_runtime.h>
#include <stdint.h>

#define H 240
#define W 320
#define NPIX (H * W)          // 76800
#define NCLS 10
#define COLS 4                // columns per vote block
#define BIN_BITS 20
#define BIN_MASK 0xFFFFFu

// d_ws layout (bytes):
//   [0,40)    uint32 cls_count[10]   (= cmask.sum per class)
//   [64,144)  u64    best[10]        (atomicMax key: (count<<20)|(MASK-bin))
//   [192,232) uint32 icnt[10]
//   [256,296) float  dsum[10]
//   [512,...) uint2  list[10][NPIX]  ({x|y<<16, slope bits})

__global__ void k_init(uint32_t* ws) {
    int i = threadIdx.x;
    if (i < 128) ws[i] = 0;   // zero first 512 bytes (all counters/keys)
}

__global__ __launch_bounds__(256) void k_compact(const int* __restrict__ label,
                                                 const float* __restrict__ cm,
                                                 uint32_t* __restrict__ cls_cnt,
                                                 uint2* __restrict__ list) {
    int p = blockIdx.x * 256 + threadIdx.x;
    if (p >= NPIX) return;
    int l = label[p];
    if (l < 1 || l > NCLS) return;
    int cls = l - 1;
    float dirx = cm[(cls * 3 + 0) * NPIX + p];
    float diry = cm[(cls * 3 + 1) * NPIX + p];
    float slope = diry / dirx;
    uint32_t idx = atomicAdd(&cls_cnt[cls], 1u);
    int y = p / W, x = p - y * W;
    uint2 e;
    e.x = (uint32_t)(x | (y << 16));
    e.y = __float_as_uint(slope);
    list[cls * NPIX + idx] = e;
}

__global__ __launch_bounds__(256) void k_vote(const uint32_t* __restrict__ cls_cnt,
                                              const uint2* __restrict__ list,
                                              unsigned long long* __restrict__ best) {
    int cls = blockIdx.y;
    int x0 = blockIdx.x * COLS;
    __shared__ uint32_t hist[COLS][H];
    __shared__ unsigned long long red[256];
    for (int i = threadIdx.x; i < COLS * H; i += 256) ((uint32_t*)hist)[i] = 0;
    __syncthreads();

    int n = (int)cls_cnt[cls];
    const uint2* lst = list + cls * NPIX;
    for (int i = threadIdx.x; i < n; i += 256) {
        uint2 e = lst[i];
        float slope = __uint_as_float(e.y);
        float xf = (float)(e.x & 0xFFFFu);
        float yf = (float)(e.x >> 16);
#pragma unroll
        for (int c = 0; c < COLS; ++c) {
            float dx = (float)(x0 + c) - xf;
            float t = yf + slope * dx;
            float r = rintf(t);                 // half-to-even == jnp.round
            // float-domain bounds check: NaN/inf/huge all fail, matching
            // reference's (y_idx>=0)&(y_idx<H) after astype(int32) on CPU.
            if (r >= 0.0f && r <= (float)(H - 1)) {
                atomicAdd(&hist[c][(int)r], 1u);
            }
        }
    }
    __syncthreads();

    // per-thread scan of the COLS*H bins -> key = (count<<20)|(MASK-bin)
    unsigned long long k = 0;
    for (int i = threadIdx.x; i < COLS * H; i += 256) {
        int c = i / H, y = i - c * H;
        uint32_t v = hist[c][y];
        uint32_t bin = (uint32_t)(y * W + x0 + c);
        unsigned long long key =
            ((unsigned long long)v << BIN_BITS) | (unsigned long long)(BIN_MASK - bin);
        if (key > k) k = key;
    }
    red[threadIdx.x] = k;
    __syncthreads();
    for (int s = 128; s > 0; s >>= 1) {
        if (threadIdx.x < s) {
            if (red[threadIdx.x + s] > red[threadIdx.x]) red[threadIdx.x] = red[threadIdx.x + s];
        }
        __syncthreads();
    }
    if (threadIdx.x == 0) atomicMax(&best[cls], red[0]);
}

__global__ __launch_bounds__(256) void k_inlier(const int* __restrict__ label,
                                                const float* __restrict__ cm,
                                                const unsigned long long* __restrict__ best,
                                                uint32_t* __restrict__ icnt,
                                                float* __restrict__ dsum) {
    int cls = blockIdx.y;
    unsigned long long key = best[cls];
    uint32_t bin = BIN_MASK - (uint32_t)(key & BIN_MASK);
    float cx = (float)(bin % W);
    float cy = (float)(bin / W);

    const float* c0p = cm + (cls * 3 + 0) * NPIX;
    const float* c1p = cm + (cls * 3 + 1) * NPIX;
    const float* c2p = cm + (cls * 3 + 2) * NPIX;

    uint32_t lcnt = 0;
    float ldsum = 0.0f;
    int base = blockIdx.x * 2560;   // 30 blocks * 2560 = 76800
    for (int i = 0; i < 10; ++i) {
        int p = base + i * 256 + threadIdx.x;
        if (label[p] == cls + 1) {
            int y = p / W, x = p - y * W;
            float disx = (float)x - cx;
            float disy = (float)y - cy;
            float dn = sqrtf(disx * disx + disy * disy);
            if (dn > 0.0f) {
                float dot = fabsf((disx / dn) * c0p[p] + (disy / dn) * c1p[p]);
                if (dot >= 0.9f) {
                    lcnt += 1;
                    ldsum += c2p[p];
                }
            }
        }
    }
    __shared__ float sd[256];
    __shared__ uint32_t sc[256];
    sd[threadIdx.x] = ldsum;
    sc[threadIdx.x] = lcnt;
    __syncthreads();
    for (int s = 128; s > 0; s >>= 1) {
        if (threadIdx.x < s) {
            sd[threadIdx.x] += sd[threadIdx.x + s];
            sc[threadIdx.x] += sc[threadIdx.x + s];
        }
        __syncthreads();
    }
    if (threadIdx.x == 0) {
        if (sc[0]) atomicAdd(&icnt[cls], sc[0]);
        if (sd[0] != 0.0f) atomicAdd(&dsum[cls], sd[0]);
    }
}

__global__ void k_final(const uint32_t* __restrict__ cls_cnt,
                        const unsigned long long* __restrict__ best,
                        const uint32_t* __restrict__ icnt,
                        const float* __restrict__ dsum,
                        float* __restrict__ out) {
    int cls = threadIdx.x;
    if (cls >= NCLS) return;
    unsigned long long key = best[cls];
    uint32_t hv = (uint32_t)(key >> BIN_BITS);
    uint32_t bin = BIN_MASK - (uint32_t)(key & BIN_MASK);
    float cx = (float)(bin % W);
    float cy = (float)(bin / W);
    bool trig = (cls_cnt[cls] >= 500u) && (hv > 500u);
    float c = (float)icnt[cls];
    float dm = (c > 0.0f) ? (dsum[cls] / fmaxf(c, 1.0f)) : __builtin_nanf("");
    out[cls * 2 + 0] = trig ? cx : 0.0f;
    out[cls * 2 + 1] = trig ? cy : 0.0f;
    out[2 * NCLS + cls] = trig ? dm : 0.0f;
}

extern "C" void kernel_launch(void* const* d_in, const int* in_sizes, int n_in,
                              void* d_out, int out_size, void* d_ws, size_t ws_size,
                              hipStream_t stream) {
    const int* label = (const int*)d_in[0];
    const float* cm = (const float*)d_in[1];
    float* out = (float*)d_out;
    char* ws = (char*)d_ws;

    uint32_t* cls_cnt = (uint32_t*)(ws + 0);
    unsigned long long* best = (unsigned long long*)(ws + 64);
    uint32_t* icnt = (uint32_t*)(ws + 192);
    float* dsum = (float*)(ws + 256);
    uint2* list = (uint2*)(ws + 512);

    k_init<<<1, 128, 0, stream>>>((uint32_t*)ws);
    k_compact<<<NPIX / 256, 256, 0, stream>>>(label, cm, cls_cnt, list);
    k_vote<<<dim3(W / COLS, NCLS), 256, 0, stream>>>(cls_cnt, list, best);
    k_inlier<<<dim3(30, NCLS), 256, 0, stream>>>(label, cm, best, icnt, dsum);
    k_final<<<1, 64, 0, stream>>>(cls_cnt, best, icnt, dsum, out);
}

// Round 2
// 108.026 us; speedup vs baseline: 3.1366x; 3.1366x over previous
//
#include <hip/hip_runtime.h>
#include <stdint.h>

#define H 240
#define W 320
#define NPIX (H * W)          // 76800
#define NCLS 10
#define COLS 4                // columns per vote block
#define BIN_BITS 20
#define BIN_MASK 0xFFFFFu

// d_ws layout (bytes):
//   [0,40)    uint32 cls_count[10]   (= cmask.sum per class)
//   [64,144)  u64    best[10]        (atomicMax key: (count<<20)|(MASK-bin))
//   [192,232) uint32 icnt[10]
//   [256,296) float  dsum[10]
//   [512,...) uint2  list[10][NPIX]  ({x|y<<16, slope bits})

__global__ void k_init(uint32_t* ws) {
    int i = threadIdx.x;
    if (i < 128) ws[i] = 0;   // zero first 512 bytes (all counters/keys)
}

// Hierarchical-aggregated compaction: LDS per-class counters -> one global
// atomicAdd per class per block (3K total vs 70K contended in R1).
__global__ __launch_bounds__(256) void k_compact(const int* __restrict__ label,
                                                 const float* __restrict__ cm,
                                                 uint32_t* __restrict__ cls_cnt,
                                                 uint2* __restrict__ list) {
    __shared__ uint32_t lcnt[NCLS];
    __shared__ uint32_t lbase[NCLS];
    int p = blockIdx.x * 256 + threadIdx.x;   // NPIX % 256 == 0, no OOB
    if (threadIdx.x < NCLS) lcnt[threadIdx.x] = 0;
    __syncthreads();

    int l = label[p];
    bool match = (l >= 1 && l <= NCLS);
    int cls = l - 1;
    uint32_t li = 0;
    if (match) li = atomicAdd(&lcnt[cls], 1u);
    __syncthreads();

    if (threadIdx.x < NCLS) {
        uint32_t c = lcnt[threadIdx.x];
        lbase[threadIdx.x] = c ? atomicAdd(&cls_cnt[threadIdx.x], c) : 0u;
    }
    __syncthreads();

    if (match) {
        float dirx = cm[(cls * 3 + 0) * NPIX + p];
        float diry = cm[(cls * 3 + 1) * NPIX + p];
        float slope = diry / dirx;
        int y = p / W, x = p - y * W;
        uint2 e;
        e.x = (uint32_t)(x | (y << 16));
        e.y = __float_as_uint(slope);
        list[cls * NPIX + lbase[cls] + li] = e;
    }
}

__global__ __launch_bounds__(256) void k_vote(const uint32_t* __restrict__ cls_cnt,
                                              const uint2* __restrict__ list,
                                              unsigned long long* __restrict__ best) {
    int cls = blockIdx.y;
    int x0 = blockIdx.x * COLS;
    __shared__ uint32_t hist[COLS][H];
    __shared__ unsigned long long red[256];
    for (int i = threadIdx.x; i < COLS * H; i += 256) ((uint32_t*)hist)[i] = 0;
    __syncthreads();

    int n = (int)cls_cnt[cls];
    const uint2* lst = list + cls * NPIX;
    for (int i = threadIdx.x; i < n; i += 256) {
        uint2 e = lst[i];
        float slope = __uint_as_float(e.y);
        float xf = (float)(e.x & 0xFFFFu);
        float yf = (float)(e.x >> 16);
#pragma unroll
        for (int c = 0; c < COLS; ++c) {
            float dx = (float)(x0 + c) - xf;
            float t = yf + slope * dx;
            float r = rintf(t);                 // half-to-even == jnp.round
            // float-domain bounds check: NaN/inf/huge all fail, matching
            // reference's (y_idx>=0)&(y_idx<H) after astype(int32) on CPU.
            if (r >= 0.0f && r <= (float)(H - 1)) {
                atomicAdd(&hist[c][(int)r], 1u);
            }
        }
    }
    __syncthreads();

    // per-thread scan of the COLS*H bins -> key = (count<<20)|(MASK-bin)
    unsigned long long k = 0;
    for (int i = threadIdx.x; i < COLS * H; i += 256) {
        int c = i / H, y = i - c * H;
        uint32_t v = hist[c][y];
        uint32_t bin = (uint32_t)(y * W + x0 + c);
        unsigned long long key =
            ((unsigned long long)v << BIN_BITS) | (unsigned long long)(BIN_MASK - bin);
        if (key > k) k = key;
    }
    red[threadIdx.x] = k;
    __syncthreads();
    for (int s = 128; s > 0; s >>= 1) {
        if (threadIdx.x < s) {
            if (red[threadIdx.x + s] > red[threadIdx.x]) red[threadIdx.x] = red[threadIdx.x + s];
        }
        __syncthreads();
    }
    if (threadIdx.x == 0) atomicMax(&best[cls], red[0]);
}

__global__ __launch_bounds__(256) void k_inlier(const int* __restrict__ label,
                                                const float* __restrict__ cm,
                                                const unsigned long long* __restrict__ best,
                                                uint32_t* __restrict__ icnt,
                                                float* __restrict__ dsum) {
    int cls = blockIdx.y;
    unsigned long long key = best[cls];
    uint32_t bin = BIN_MASK - (uint32_t)(key & BIN_MASK);
    float cx = (float)(bin % W);
    float cy = (float)(bin / W);

    const float* c0p = cm + (cls * 3 + 0) * NPIX;
    const float* c1p = cm + (cls * 3 + 1) * NPIX;
    const float* c2p = cm + (cls * 3 + 2) * NPIX;

    uint32_t lcnt = 0;
    float ldsum = 0.0f;
    int base = blockIdx.x * 2560;   // 30 blocks * 2560 = 76800
    for (int i = 0; i < 10; ++i) {
        int p = base + i * 256 + threadIdx.x;
        if (label[p] == cls + 1) {
            int y = p / W, x = p - y * W;
            float disx = (float)x - cx;
            float disy = (float)y - cy;
            float dn = sqrtf(disx * disx + disy * disy);
            if (dn > 0.0f) {
                float dot = fabsf((disx / dn) * c0p[p] + (disy / dn) * c1p[p]);
                if (dot >= 0.9f) {
                    lcnt += 1;
                    ldsum += c2p[p];
                }
            }
        }
    }
    __shared__ float sd[256];
    __shared__ uint32_t sc[256];
    sd[threadIdx.x] = ldsum;
    sc[threadIdx.x] = lcnt;
    __syncthreads();
    for (int s = 128; s > 0; s >>= 1) {
        if (threadIdx.x < s) {
            sd[threadIdx.x] += sd[threadIdx.x + s];
            sc[threadIdx.x] += sc[threadIdx.x + s];
        }
        __syncthreads();
    }
    if (threadIdx.x == 0) {
        if (sc[0]) atomicAdd(&icnt[cls], sc[0]);
        if (sd[0] != 0.0f) atomicAdd(&dsum[cls], sd[0]);
    }
}

__global__ void k_final(const uint32_t* __restrict__ cls_cnt,
                        const unsigned long long* __restrict__ best,
                        const uint32_t* __restrict__ icnt,
                        const float* __restrict__ dsum,
                        float* __restrict__ out) {
    int cls = threadIdx.x;
    if (cls >= NCLS) return;
    unsigned long long key = best[cls];
    uint32_t hv = (uint32_t)(key >> BIN_BITS);
    uint32_t bin = BIN_MASK - (uint32_t)(key & BIN_MASK);
    float cx = (float)(bin % W);
    float cy = (float)(bin / W);
    bool trig = (cls_cnt[cls] >= 500u) && (hv > 500u);
    float c = (float)icnt[cls];
    float dm = (c > 0.0f) ? (dsum[cls] / fmaxf(c, 1.0f)) : __builtin_nanf("");
    out[cls * 2 + 0] = trig ? cx : 0.0f;
    out[cls * 2 + 1] = trig ? cy : 0.0f;
    out[2 * NCLS + cls] = trig ? dm : 0.0f;
}

extern "C" void kernel_launch(void* const* d_in, const int* in_sizes, int n_in,
                              void* d_out, int out_size, void* d_ws, size_t ws_size,
                              hipStream_t stream) {
    const int* label = (const int*)d_in[0];
    const float* cm = (const float*)d_in[1];
    float* out = (float*)d_out;
    char* ws = (char*)d_ws;

    uint32_t* cls_cnt = (uint32_t*)(ws + 0);
    unsigned long long* best = (unsigned long long*)(ws + 64);
    uint32_t* icnt = (uint32_t*)(ws + 192);
    float* dsum = (float*)(ws + 256);
    uint2* list = (uint2*)(ws + 512);

    k_init<<<1, 128, 0, stream>>>((uint32_t*)ws);
    k_compact<<<NPIX / 256, 256, 0, stream>>>(label, cm, cls_cnt, list);
    k_vote<<<dim3(W / COLS, NCLS), 256, 0, stream>>>(cls_cnt, list, best);
    k_inlier<<<dim3(30, NCLS), 256, 0, stream>>>(label, cm, best, icnt, dsum);
    k_final<<<1, 64, 0, stream>>>(cls_cnt, best, icnt, dsum, out);
}